// Round 3
// baseline (1711.138 us; speedup 1.0000x reference)
//
#include <hip/hip_runtime.h>

// SPRTFlipLinear: y = x @ W^T, W = ternary * per-128-group scales.
// M=8192, N=4096, K=4096. 274.9 GFLOP/call.
// R6: FUSED single kernel — dequant (int32 ternary * scale -> bf16) and
//     x f32->bf16 conversion happen during LDS staging (reg-staged, T14):
//     no prep kernel, no workspace round-trip (R2 showed ~270us of the 525
//     was prep + workspace overhead while GEMM was only 255).
//     Structure: 256x256 tile, BK=64, 8 waves, double-buffered LDS,
//     1 barrier/tile: {cvt+ds_write tile t+1} {issue loads t+2} {MFMA tile t}.
//     Loads in flight across a full tile (~2000cy) >> HBM latency.
//     LDS layout/swizzle + read/MFMA/epilogue geometry verbatim from the
//     harness-verified R5 kernel; per-tile MFMA order identical -> same output.

#define IN_F  4096
#define OUT_F 4096
#define MROWS 8192

#define BM 256
#define BN 256
#define BK 64
#define NKT (IN_F / BK)  // 64 K-tiles

using bf16x8 = __attribute__((ext_vector_type(8))) __bf16;
using f32x16 = __attribute__((ext_vector_type(16))) float;

#define FENCE asm volatile("" ::: "memory")
// Raw barrier with LDS drain only — vmcnt (prefetch) stays in flight.
#define TILEBAR() do { \
    asm volatile("s_waitcnt lgkmcnt(0)" ::: "memory"); \
    __builtin_amdgcn_sched_barrier(0); \
    __builtin_amdgcn_s_barrier(); \
    __builtin_amdgcn_sched_barrier(0); \
    FENCE; \
  } while (0)

// LDS byte map (131072 B): A: buf*32768 + half*16384 ; B: 65536 + buf*32768 + half*16384.
// Within a half: row r (0..127) at r*128; 16B slot s of row r holds global k-chunk
// s ^ (r&7) ^ ((r>>3)&7)  (same involution as R5; realized here on the ds_write side
// by sourcing global chunk gc = slot ^ (r&7) ^ ((r>>3)&7) into linear slot order).

__global__ __launch_bounds__(512, 2) void fused_gemm(const float* __restrict__ X,
                                                     const int* __restrict__ T,
                                                     const float* __restrict__ S,
                                                     float* __restrict__ C) {
  __shared__ unsigned short lds[65536];  // 128 KiB

  const int tid  = threadIdx.x;
  const int lane = tid & 63;
  const int wv   = tid >> 6;      // 0..7
  const int wm   = wv & 1;        // M pair (rows wm*64 and 128+wm*64)
  const int wn   = wv >> 1;       // N quad (cols wn*32 and 128+wn*32)
  const int r32  = lane & 31;
  const int kh   = lane >> 5;     // k-half of fragment
  const int srow = lane >> 3;
  const int l7   = lane & 7;

  // bijective XCD chunk swizzle: 512 blocks -> 8 XCDs x (8 rows x 8 cols) chunks
  const int bid = blockIdx.x;
  const int xcd = bid & 7;
  const int loc = bid >> 3;                    // 0..63
  const int by  = (xcd >> 1) * 8 + (loc >> 3); // 0..31
  const int bx  = (xcd & 1) * 8 + (loc & 7);   // 0..15
  const int m0  = by * BM;
  const int n0  = bx * BN;

  // ---- staging geometry: 4 (half,inst) combos per wave for A and for B.
  // combo hi: h=hi>>1, i=hi&1; chunk ch=wv*2+i (8 rows x 8 slots of 16B);
  // lane covers (row = h*128 + ch*8 + srow, slot l7) sourcing global k-chunk
  // gc = l7 ^ srow ^ (ch&7). Scale group for B row at k-tile kt: (kt*64)>>7
  // (chunk-independent since gc*8+7 < 64 <= k-tile span).
  int offGA[4], offGB[4], sgB[4], ldsA[4], ldsB[4];
#pragma unroll
  for (int hi = 0; hi < 4; ++hi) {
    const int h  = hi >> 1, i = hi & 1;
    const int ch = wv * 2 + i;
    const int row = h * 128 + ch * 8 + srow;
    const int gc  = l7 ^ srow ^ (ch & 7);
    offGA[hi] = (m0 + row) * IN_F + gc * 8;
    offGB[hi] = (n0 + row) * IN_F + gc * 8;
    sgB[hi]   = (n0 + row) * (IN_F / 128);
    ldsA[hi]  = h * 16384 + ch * 1024 + lane * 16;           // == gload_lds dest of R5
    ldsB[hi]  = 65536 + h * 16384 + ch * 1024 + lane * 16;
  }

  float4 rA[8];  // tile-in-flight A (f32), 8 x 16B per lane
  int4   rB[8];  // tile-in-flight B (int32)
  float  rS[4];  // per-(half,inst) scale

#define ISSUE_T(kt) do { const int kc_ = (kt) * BK; \
    _Pragma("unroll") for (int hi = 0; hi < 4; ++hi) { \
      rA[hi*2+0] = *(const float4*)(X + offGA[hi] + kc_); \
      rA[hi*2+1] = *(const float4*)(X + offGA[hi] + kc_ + 4); } \
    _Pragma("unroll") for (int hi = 0; hi < 4; ++hi) { \
      rB[hi*2+0] = *(const int4*)(T + offGB[hi] + kc_); \
      rB[hi*2+1] = *(const int4*)(T + offGB[hi] + kc_ + 4); \
      rS[hi] = S[sgB[hi] + ((kc_) >> 7)]; } \
  } while (0)

  // cvt+write: (__bf16) cast is RNE — bitwise identical to the old f2bf path.
#define CVTWRITE(cd) do { \
    _Pragma("unroll") for (int hi = 0; hi < 4; ++hi) { \
      bf16x8 oa; \
      oa[0] = (__bf16)rA[hi*2+0].x; oa[1] = (__bf16)rA[hi*2+0].y; \
      oa[2] = (__bf16)rA[hi*2+0].z; oa[3] = (__bf16)rA[hi*2+0].w; \
      oa[4] = (__bf16)rA[hi*2+1].x; oa[5] = (__bf16)rA[hi*2+1].y; \
      oa[6] = (__bf16)rA[hi*2+1].z; oa[7] = (__bf16)rA[hi*2+1].w; \
      *(bf16x8*)((char*)lds + (cd) * 32768 + ldsA[hi]) = oa; } \
    _Pragma("unroll") for (int hi = 0; hi < 4; ++hi) { \
      const float s0_ = rS[hi]; bf16x8 ob; \
      ob[0] = (__bf16)((float)rB[hi*2+0].x * s0_); ob[1] = (__bf16)((float)rB[hi*2+0].y * s0_); \
      ob[2] = (__bf16)((float)rB[hi*2+0].z * s0_); ob[3] = (__bf16)((float)rB[hi*2+0].w * s0_); \
      ob[4] = (__bf16)((float)rB[hi*2+1].x * s0_); ob[5] = (__bf16)((float)rB[hi*2+1].y * s0_); \
      ob[6] = (__bf16)((float)rB[hi*2+1].z * s0_); ob[7] = (__bf16)((float)rB[hi*2+1].w * s0_); \
      *(bf16x8*)((char*)lds + (cd) * 32768 + ldsB[hi]) = ob; } \
  } while (0)

  // ---- read geometry (verbatim R5): byte offsets, buf/half added at use
  const int rA_ = wm * 64 + r32;   // A row-in-half for sm=0 (sm adds 32)
  const int rB_ = wn * 32 + r32;   // B row-in-half
  int offA[2][4];
  int offB[4];
#pragma unroll
  for (int sm = 0; sm < 2; ++sm) {
    const int fh = ((sm * 4) + (r32 >> 3)) & 7;
#pragma unroll
    for (int k4 = 0; k4 < 4; ++k4) {
      const int pc = (2 * k4 + kh) ^ (r32 & 7) ^ fh;
      offA[sm][k4] = (rA_ + sm * 32) * 128 + pc * 16;
    }
  }
  {
    const int fh = ((wn * 4) + (r32 >> 3)) & 7;
#pragma unroll
    for (int k4 = 0; k4 < 4; ++k4) {
      const int pc = (2 * k4 + kh) ^ (r32 & 7) ^ fh;
      offB[k4] = 65536 + rB_ * 128 + pc * 16;
    }
  }

  bf16x8 af[2][4], bf[2][4];

#define READ_A(cb, qm) do { \
    _Pragma("unroll") for (int sm = 0; sm < 2; ++sm) \
    _Pragma("unroll") for (int k4 = 0; k4 < 4; ++k4) \
      af[sm][k4] = *(const bf16x8*)((const char*)lds + offA[sm][k4] + (cb) * 32768 + (qm) * 16384); \
  } while (0)

#define READ_B(cb, qn) do { \
    _Pragma("unroll") for (int k4 = 0; k4 < 4; ++k4) \
      bf[qn][k4] = *(const bf16x8*)((const char*)lds + offB[k4] + (cb) * 32768 + (qn) * 16384); \
  } while (0)

#define MFMA_Q(qm, qn) do { \
    __builtin_amdgcn_s_setprio(1); \
    _Pragma("unroll") for (int sm = 0; sm < 2; ++sm) \
    _Pragma("unroll") for (int k4 = 0; k4 < 4; ++k4) \
      acc[qm][sm][qn] = __builtin_amdgcn_mfma_f32_32x32x16_bf16(af[sm][k4], bf[qn][k4], acc[qm][sm][qn], 0, 0, 0); \
    __builtin_amdgcn_s_setprio(0); \
  } while (0)

  f32x16 acc[2][2][2];
#pragma unroll
  for (int a = 0; a < 2; ++a)
#pragma unroll
    for (int b = 0; b < 2; ++b)
#pragma unroll
      for (int c2 = 0; c2 < 2; ++c2)
        acc[a][b][c2] = (f32x16)(0.0f);

  // ---- prologue: tile0 -> regs -> buf0; issue tile1; barrier.
  ISSUE_T(0);
  CVTWRITE(0);          // compiler inserts the vmcnt wait before first use
  ISSUE_T(1);
  TILEBAR();

  int c = 0;
#pragma unroll 1
  for (int t = 0; t < NKT; ++t) {
    // write tile t+1 (loads issued a full tile ago -> landed) into the idle buf;
    // that buf's last reads drained at the previous TILEBAR (WAR safe).
    if (t + 1 < NKT) CVTWRITE(c ^ 1);
    // issue tile t+2 into the just-consumed staging regs; in flight across
    // this tile's MFMAs + barrier (~2000cy cover).
    if (t + 2 < NKT) ISSUE_T(t + 2);

    // compute tile t from buf c (no intra-tile barriers needed)
    READ_A(c, 0); READ_B(c, 0);
    MFMA_Q(0, 0);
    READ_B(c, 1);
    MFMA_Q(0, 1);
    READ_A(c, 1);
    MFMA_Q(1, 0);
    MFMA_Q(1, 1);

    TILEBAR();  // writes(c^1) visible to all; reads(c) drained before next overwrite
    c ^= 1;
  }

  // ---- epilogue (verbatim R5): col = lane&31, row = (reg&3)+8*(reg>>2)+4*(lane>>5)
#pragma unroll
  for (int qm = 0; qm < 2; ++qm)
#pragma unroll
    for (int sm = 0; sm < 2; ++sm)
#pragma unroll
      for (int qn = 0; qn < 2; ++qn) {
        const int ncol = n0 + qn * 128 + wn * 32 + r32;
        const int mb   = m0 + qm * 128 + wm * 64 + sm * 32 + 4 * kh;
#pragma unroll
        for (int r = 0; r < 16; ++r) {
          const int mrow = mb + (r & 3) + 8 * (r >> 2);
          C[(size_t)mrow * OUT_F + ncol] = acc[qm][sm][qn][r];
        }
      }
}

extern "C" void kernel_launch(void* const* d_in, const int* in_sizes, int n_in,
                              void* d_out, int out_size, void* d_ws, size_t ws_size,
                              hipStream_t stream) {
  const float* x       = (const float*)d_in[0];   // [4,2048,4096] f32
  const int*   ternary = (const int*)d_in[1];     // [4096,4096] int {-1,0,1}
  const float* scales  = (const float*)d_in[2];   // [131072] f32
  float* out = (float*)d_out;                     // [4,2048,4096] f32

  (void)d_ws; (void)ws_size;  // workspace eliminated — no prep pass, no poison cost

  fused_gemm<<<(MROWS / BM) * (OUT_F / BN), 512, 0, stream>>>(x, ternary, scales, out);
}

// Round 4
// 495.818 us; speedup vs baseline: 3.4511x; 3.4511x over previous
//
#include <hip/hip_runtime.h>

// SPRTFlipLinear: y = x @ W^T, W = ternary * per-128-group scales.
// M=8192, N=4096, K=4096. 274.9 GFLOP/call.
// R7: revert R6 fusion (reg-staged full tile spilled: WRITE_SIZE 1.44GB vs
//     134MB output = scratch traffic, MfmaUtil 7%). Two-kernel again:
//     - GEMM: byte-identical to the R5-verified 256x256 8-phase kernel
//       (255us, MfmaUtil 50.7%, 0 bank conflicts).
//     - prep: rewritten for dense coalescing. R6 measured fixed harness
//       overhead = 135us => R5 prep was ~135us (2.2 TB/s on 302MB).
//       Old pattern loaded 2x float4 at 32B lane stride (half-utilized
//       lines per instr). New: one-shot region-split, 4 contiguous f32
//       per lane = dense 1KB/wave loads, 512B/wave stores. Target ~55us.

#define IN_F  4096
#define OUT_F 4096
#define MROWS 8192
#define GROUP 128

#define BM 256
#define BN 256
#define BK 64
#define NKT   (IN_F / BK)   // 64 K-tiles
#define NITER (NKT / 2)     // 32 double-tile iterations

// prep geometry: 4 elems/thread, 256 thr/block
#define XBLK ((MROWS * IN_F) / 4 / 256)   // 32768 blocks for x cvt
#define WBLK ((OUT_F * IN_F) / 4 / 256)   // 16384 blocks for w dequant

using bf16x8 = __attribute__((ext_vector_type(8))) __bf16;
using f32x16 = __attribute__((ext_vector_type(16))) float;

#define GLOBAL_AS __attribute__((address_space(1)))
#define LDS_AS    __attribute__((address_space(3)))

__device__ __forceinline__ unsigned short f2bf(float f) {
  unsigned int u = __float_as_uint(f);
  u += 0x7fffu + ((u >> 16) & 1u);
  return (unsigned short)(u >> 16);
}

// One-shot prep, dense coalescing: lane i handles 4 contiguous elems
// (16B load / 8B store per lane; wave = 1KB dense load, 512B dense store).
__global__ void prep_kernel(const float* __restrict__ x, unsigned short* __restrict__ xb,
                            const int* __restrict__ t, const float* __restrict__ s,
                            unsigned short* __restrict__ wb) {
  const int b = blockIdx.x;
  if (b < XBLK) {
    const int i = (b * 256 + (int)threadIdx.x) * 4;
    const float4 a = *(const float4*)(x + i);
    ushort4 o;
    o.x = f2bf(a.x); o.y = f2bf(a.y); o.z = f2bf(a.z); o.w = f2bf(a.w);
    *(ushort4*)(xb + i) = o;
  } else {
    const int i = ((b - XBLK) * 256 + (int)threadIdx.x) * 4;
    const float sc = s[i >> 7];  // GROUP=128; 4 | 128 so one scale per lane
    const int4 tv = *(const int4*)(t + i);
    ushort4 o;
    o.x = f2bf((float)tv.x * sc); o.y = f2bf((float)tv.y * sc);
    o.z = f2bf((float)tv.z * sc); o.w = f2bf((float)tv.w * sc);
    *(ushort4*)(wb + i) = o;
  }
}

// ---------------- 256x256 8-phase GEMM (R5-verified, unchanged) ----------------
// C[M][N] = A[M][K]*B[N][K]^T, bf16 in fp32 out. 512 threads = 8 waves (2M x 4N),
// wave tile 128x64 as 4 quadrants of 64x32 (2 Mfrags x 1 Nfrag of 32x32x16, 4 ksteps).
// Quadrant->half mapping: wave wm rows {wm*64, 128+wm*64}, wave wn cols {wn*32, 128+wn*32},
// so ALL waves consume A-half0/B-half0 early and A-half1/B-half1 late -> half-tile
// staging of tile t+2 into the just-consumed regions of the live buffer is race-free
// (each stage issue is >=1 barrier after the region's last ds_read drained).
//
// LDS byte map (131072 B): A: buf*32768 + half*16384 ; B: 65536 + buf*32768 + half*16384.
// Within a half: row r (0..127) at r*128; 16B slot s of row r holds global k-chunk
// s ^ (r&7) ^ ((r>>3)&7)  (involution; realized by permuting the per-lane GLOBAL source,
// gload_lds dest stays linear = base + lane*16).
//
// vmcnt ledger (per wave, 2 loads per stage): steady state at P4/P8 there are 14
// outstanding; vmcnt(6) drains the 8 oldest = exactly one full K-tile, leaving 3
// half-tiles (6 loads) in flight. Prologue: 14 outstanding -> vmcnt(6) = tile0 landed.
// Final iter: P4 VMBAR(0) drains tile63 fully before buf1 reads; P8 plain BAR.

#define FENCE asm volatile("" ::: "memory")
#define BAR() do { FENCE; __builtin_amdgcn_s_barrier(); FENCE; } while (0)
#define VMBAR(N) do { asm volatile("s_waitcnt vmcnt(" #N ")" ::: "memory"); \
                      __builtin_amdgcn_s_barrier(); FENCE; } while (0)

__global__ __launch_bounds__(512, 2) void gemm_bt_kernel(const unsigned short* __restrict__ A,
                                                         const unsigned short* __restrict__ B,
                                                         float* __restrict__ C) {
  __shared__ unsigned short lds[65536];  // 128 KiB

  const int tid  = threadIdx.x;
  const int lane = tid & 63;
  const int wv   = tid >> 6;      // 0..7
  const int wm   = wv & 1;        // M pair (rows wm*64 and 128+wm*64)
  const int wn   = wv >> 1;       // N quad (cols wn*32 and 128+wn*32)
  const int r32  = lane & 31;
  const int kh   = lane >> 5;     // k-half of fragment

  // bijective XCD chunk swizzle: 512 blocks -> 8 XCDs x (8 rows x 8 cols) chunks
  const int bid = blockIdx.x;
  const int xcd = bid & 7;
  const int loc = bid >> 3;                    // 0..63
  const int by  = (xcd >> 1) * 8 + (loc >> 3); // 0..31
  const int bx  = (xcd & 1) * 8 + (loc & 7);   // 0..15
  const int m0  = by * BM;
  const int n0  = bx * BN;

  // ---- staging geometry: instruction i covers chunk = wv*2+i (8 rows x 8 slots);
  // lane slot (srow = lane>>3, lane&7); source k-chunk = (lane&7) ^ srow ^ (chunk&7).
  const int srow = lane >> 3;
  const int l7   = lane & 7;
  const int rowoff0 = (wv * 2 + 0) * 8 + srow;
  const int rowoff1 = (wv * 2 + 1) * 8 + srow;
  const int sc0 = (l7 ^ srow ^ ((wv * 2 + 0) & 7)) * 8;
  const int sc1 = (l7 ^ srow ^ ((wv * 2 + 1) & 7)) * 8;
  const unsigned short* pA0 = A + (size_t)(m0 + rowoff0) * IN_F + sc0;
  const unsigned short* pA1 = A + (size_t)(m0 + rowoff1) * IN_F + sc1;
  const unsigned short* pB0 = B + (size_t)(n0 + rowoff0) * IN_F + sc0;
  const unsigned short* pB1 = B + (size_t)(n0 + rowoff1) * IN_F + sc1;

#define STAGE_A(bufi, h, kcol) do { \
    __builtin_amdgcn_global_load_lds((const GLOBAL_AS unsigned int*)(pA0 + (size_t)(h) * 128 * IN_F + (kcol)), \
        (LDS_AS unsigned int*)((char*)lds + (bufi) * 32768 + (h) * 16384 + (wv * 2 + 0) * 1024), 16, 0, 0); \
    __builtin_amdgcn_global_load_lds((const GLOBAL_AS unsigned int*)(pA1 + (size_t)(h) * 128 * IN_F + (kcol)), \
        (LDS_AS unsigned int*)((char*)lds + (bufi) * 32768 + (h) * 16384 + (wv * 2 + 1) * 1024), 16, 0, 0); \
  } while (0)

#define STAGE_B(bufi, h, kcol) do { \
    __builtin_amdgcn_global_load_lds((const GLOBAL_AS unsigned int*)(pB0 + (size_t)(h) * 128 * IN_F + (kcol)), \
        (LDS_AS unsigned int*)((char*)lds + 65536 + (bufi) * 32768 + (h) * 16384 + (wv * 2 + 0) * 1024), 16, 0, 0); \
    __builtin_amdgcn_global_load_lds((const GLOBAL_AS unsigned int*)(pB1 + (size_t)(h) * 128 * IN_F + (kcol)), \
        (LDS_AS unsigned int*)((char*)lds + 65536 + (bufi) * 32768 + (h) * 16384 + (wv * 2 + 1) * 1024), 16, 0, 0); \
  } while (0)

  // ---- read geometry: precomputed byte offsets (buf/half added as imm at the read)
  const int rA = wm * 64 + r32;   // A row-in-half for sm=0 (sm adds 32)
  const int rB = wn * 32 + r32;   // B row-in-half
  int offA[2][4];
  int offB[4];
#pragma unroll
  for (int sm = 0; sm < 2; ++sm) {
    const int fh = ((sm * 4) + (r32 >> 3)) & 7;   // ((row>>3)&7); wm*8 drops mod 8
#pragma unroll
    for (int k4 = 0; k4 < 4; ++k4) {
      const int pc = (2 * k4 + kh) ^ (r32 & 7) ^ fh;
      offA[sm][k4] = (rA + sm * 32) * 128 + pc * 16;
    }
  }
  {
    const int fh = ((wn * 4) + (r32 >> 3)) & 7;
#pragma unroll
    for (int k4 = 0; k4 < 4; ++k4) {
      const int pc = (2 * k4 + kh) ^ (r32 & 7) ^ fh;
      offB[k4] = 65536 + rB * 128 + pc * 16;
    }
  }

  bf16x8 af[2][4], bf[2][4];

#define READ_A(bufi, qm) do { \
    _Pragma("unroll") for (int sm = 0; sm < 2; ++sm) \
    _Pragma("unroll") for (int k4 = 0; k4 < 4; ++k4) \
      af[sm][k4] = *(const bf16x8*)((const char*)lds + offA[sm][k4] + (bufi) * 32768 + (qm) * 16384); \
  } while (0)

#define READ_B(bufi, qn) do { \
    _Pragma("unroll") for (int k4 = 0; k4 < 4; ++k4) \
      bf[qn][k4] = *(const bf16x8*)((const char*)lds + offB[k4] + (bufi) * 32768 + (qn) * 16384); \
  } while (0)

#define MFMA_Q(qm, qn) do { \
    __builtin_amdgcn_s_setprio(1); \
    _Pragma("unroll") for (int sm = 0; sm < 2; ++sm) \
    _Pragma("unroll") for (int k4 = 0; k4 < 4; ++k4) \
      acc[qm][sm][qn] = __builtin_amdgcn_mfma_f32_32x32x16_bf16(af[sm][k4], bf[qn][k4], acc[qm][sm][qn], 0, 0, 0); \
    __builtin_amdgcn_s_setprio(0); \
  } while (0)

  f32x16 acc[2][2][2];
#pragma unroll
  for (int a = 0; a < 2; ++a)
#pragma unroll
    for (int b = 0; b < 2; ++b)
#pragma unroll
      for (int c = 0; c < 2; ++c)
        acc[a][b][c] = (f32x16)(0.0f);

  // ---- prologue: tile0 -> buf0 (A0,B0,B1,A1), tile1 -> buf1 (A0,B0,B1). 14 loads.
  STAGE_A(0, 0, 0); STAGE_B(0, 0, 0); STAGE_B(0, 1, 0); STAGE_A(0, 1, 0);
  STAGE_A(1, 0, BK); STAGE_B(1, 0, BK); STAGE_B(1, 1, BK);
  VMBAR(6);  // tile0 fully landed; tile1 A0/B0/B1 in flight

#pragma unroll 1
  for (int j = 0; j < NITER; ++j) {
    const int ku = (2 * j + 1) * BK;
    const int k2 = (2 * j + 2) * BK;
    const int k3 = (2 * j + 3) * BK;
    const bool more = (j < NITER - 1);

    // P1: tile t quadrant (Alow,Bleft); stage u.A1 (buf1.A.h1 last read prev P7)
    READ_A(0, 0); READ_B(0, 0);
    STAGE_A(1, 1, ku);
    BAR(); MFMA_Q(0, 0); BAR();

    // P2: (Alow,Bright); stage t+2.A0 (buf0.A.h0 last read P1)
    READ_B(0, 1);
    if (more) STAGE_A(0, 0, k2);
    BAR(); MFMA_Q(0, 1); BAR();

    // P3: (Ahigh,Bleft); stage t+2.B0 (buf0.B.h0 last read P1)
    READ_A(0, 1);
    if (more) STAGE_B(0, 0, k2);
    BAR(); MFMA_Q(1, 0); BAR();

    // P4: (Ahigh,Bright); stage t+2.B1 (buf0.B.h1 last read P2); wait tile u landed
    if (more) STAGE_B(0, 1, k2);
    BAR(); MFMA_Q(1, 1);
    if (more) { VMBAR(6); } else { VMBAR(0); }

    // P5: tile u quadrant (Alow,Bleft); stage t+2.A1 (buf0.A.h1 last read P3)
    READ_A(1, 0); READ_B(1, 0);
    if (more) STAGE_A(0, 1, k2);
    BAR(); MFMA_Q(0, 0); BAR();

    // P6: (Alow,Bright); stage t+3.A0 (buf1.A.h0 last read P5)
    READ_B(1, 1);
    if (more) STAGE_A(1, 0, k3);
    BAR(); MFMA_Q(0, 1); BAR();

    // P7: (Ahigh,Bleft); stage t+3.B0 (buf1.B.h0 last read P5)
    READ_A(1, 1);
    if (more) STAGE_B(1, 0, k3);
    BAR(); MFMA_Q(1, 0); BAR();

    // P8: (Ahigh,Bright); stage t+3.B1 (buf1.B.h1 last read P6); wait tile t+2 landed
    if (more) STAGE_B(1, 1, k3);
    BAR(); MFMA_Q(1, 1);
    if (more) { VMBAR(6); } else { BAR(); }
  }

  // ---- epilogue: C/D layout col = lane&31, row = (reg&3)+8*(reg>>2)+4*(lane>>5)
#pragma unroll
  for (int qm = 0; qm < 2; ++qm)
#pragma unroll
    for (int sm = 0; sm < 2; ++sm)
#pragma unroll
      for (int qn = 0; qn < 2; ++qn) {
        const int ncol = n0 + qn * 128 + wn * 32 + r32;
        const int mb   = m0 + qm * 128 + wm * 64 + sm * 32 + 4 * kh;
#pragma unroll
        for (int r = 0; r < 16; ++r) {
          const int mrow = mb + (r & 3) + 8 * (r >> 2);
          C[(size_t)mrow * OUT_F + ncol] = acc[qm][sm][qn][r];
        }
      }
}

extern "C" void kernel_launch(void* const* d_in, const int* in_sizes, int n_in,
                              void* d_out, int out_size, void* d_ws, size_t ws_size,
                              hipStream_t stream) {
  const float* x       = (const float*)d_in[0];   // [4,2048,4096] f32
  const int*   ternary = (const int*)d_in[1];     // [4096,4096] int {-1,0,1}
  const float* scales  = (const float*)d_in[2];   // [131072] f32
  float* out = (float*)d_out;                     // [4,2048,4096] f32

  unsigned short* xb = (unsigned short*)d_ws;                 // 67.1 MB
  unsigned short* wb = xb + (size_t)MROWS * IN_F;             // +33.6 MB

  prep_kernel<<<XBLK + WBLK, 256, 0, stream>>>(x, xb, ternary, scales, wb);

  gemm_bt_kernel<<<(MROWS / BM) * (OUT_F / BN), 512, 0, stream>>>(xb, wb, out);
}

// Round 5
// 488.351 us; speedup vs baseline: 3.5039x; 1.0153x over previous
//
#include <hip/hip_runtime.h>

// SPRTFlipLinear: y = x @ W^T, W = ternary * per-128-group scales.
// M=8192, N=4096, K=4096. 274.9 GFLOP/call.
// R8: (a) GEMM: drop the 8 redundant MID-phase barriers (keep end-phase
//     barriers + P4/P8 counted VMBARs). Audit: every stage-overwrite is
//     >=1 end-phase barrier after its region's last read (A0:P1->P2,
//     B0:P1->P3, B1:P2->P4, A1:P3->P5; buf1 symmetric; A1:P7->next P1).
//     DMA visibility still gated by VMBAR(6) at P4/P8. With 1 block/CU
//     (128KiB LDS) all 8 waves were lock-stepped on 16 barriers/iter;
//     8/iter lets waves drift so ds_read and MFMA pipes overlap.
//     (b) prep: revert to the R0 one-shot 8-elem/lane pattern (fastest
//     measured variant: ~86us vs 98/122 for R7/R5 styles).

#define IN_F  4096
#define OUT_F 4096
#define MROWS 8192
#define GROUP 128

#define BM 256
#define BN 256
#define BK 64
#define NKT   (IN_F / BK)   // 64 K-tiles
#define NITER (NKT / 2)     // 32 double-tile iterations

#define CVT_BLOCKS ((MROWS * IN_F) / 8 / 256)   // 16384
#define DQ_BLOCKS  ((OUT_F * IN_F) / 8 / 256)   // 8192

using bf16x8 = __attribute__((ext_vector_type(8))) __bf16;
using f32x16 = __attribute__((ext_vector_type(16))) float;

#define GLOBAL_AS __attribute__((address_space(1)))
#define LDS_AS    __attribute__((address_space(3)))

__device__ __forceinline__ unsigned short f2bf(float f) {
  unsigned int u = __float_as_uint(f);
  u += 0x7fffu + ((u >> 16) & 1u);
  return (unsigned short)(u >> 16);
}

// One-shot prep (R0 pattern): blocks [0, CVT_BLOCKS) convert x f32->bf16
// (8 elems/lane: 2x float4 load, 1x uint4 store); rest dequant ternary->bf16.
__global__ void prep_kernel(const float* __restrict__ x, unsigned short* __restrict__ xb,
                            const int* __restrict__ t, const float* __restrict__ s,
                            unsigned short* __restrict__ wb) {
  int b = blockIdx.x;
  if (b < CVT_BLOCKS) {
    const int i = (b * 256 + (int)threadIdx.x) * 8;
    const float4 a0 = *(const float4*)(x + i);
    const float4 a1 = *(const float4*)(x + i + 4);
    union { unsigned short u[8]; uint4 v; } o;
    o.u[0] = f2bf(a0.x); o.u[1] = f2bf(a0.y); o.u[2] = f2bf(a0.z); o.u[3] = f2bf(a0.w);
    o.u[4] = f2bf(a1.x); o.u[5] = f2bf(a1.y); o.u[6] = f2bf(a1.z); o.u[7] = f2bf(a1.w);
    *(uint4*)(xb + i) = o.v;
  } else {
    const int i = ((b - CVT_BLOCKS) * 256 + (int)threadIdx.x) * 8;
    const float sc = s[i >> 7];  // GROUP=128
    const int4 t0 = *(const int4*)(t + i);
    const int4 t1 = *(const int4*)(t + i + 4);
    union { unsigned short u[8]; uint4 v; } o;
    o.u[0] = f2bf((float)t0.x * sc); o.u[1] = f2bf((float)t0.y * sc);
    o.u[2] = f2bf((float)t0.z * sc); o.u[3] = f2bf((float)t0.w * sc);
    o.u[4] = f2bf((float)t1.x * sc); o.u[5] = f2bf((float)t1.y * sc);
    o.u[6] = f2bf((float)t1.z * sc); o.u[7] = f2bf((float)t1.w * sc);
    *(uint4*)(wb + i) = o.v;
  }
}

// ---------------- 256x256 8-phase GEMM ----------------
// C[M][N] = A[M][K]*B[N][K]^T, bf16 in fp32 out. 512 threads = 8 waves (2M x 4N),
// wave tile 128x64 as 4 quadrants of 64x32 (2 Mfrags x 1 Nfrag of 32x32x16, 4 ksteps).
//
// LDS byte map (131072 B): A: buf*32768 + half*16384 ; B: 65536 + buf*32768 + half*16384.
// Within a half: row r (0..127) at r*128; 16B slot s of row r holds global k-chunk
// s ^ (r&7) ^ ((r>>3)&7)  (involution; realized by permuting the per-lane GLOBAL source,
// gload_lds dest stays linear = base + lane*16).
//
// vmcnt ledger (per wave, 2 loads per stage): steady state at P4/P8 there are 14
// outstanding; vmcnt(6) drains the 8 oldest = exactly one full K-tile, leaving 3
// half-tiles (6 loads) in flight. Prologue: 14 outstanding -> vmcnt(6) = tile0 landed.
// Final iter: P4 VMBAR(0) drains tile63 fully before buf1 reads; P8 plain BAR.
//
// R8: ONE barrier per phase (end-phase). WAR audit in file header.

#define FENCE asm volatile("" ::: "memory")
#define BAR() do { FENCE; __builtin_amdgcn_s_barrier(); FENCE; } while (0)
#define VMBAR(N) do { asm volatile("s_waitcnt vmcnt(" #N ")" ::: "memory"); \
                      __builtin_amdgcn_s_barrier(); FENCE; } while (0)

__global__ __launch_bounds__(512, 2) void gemm_bt_kernel(const unsigned short* __restrict__ A,
                                                         const unsigned short* __restrict__ B,
                                                         float* __restrict__ C) {
  __shared__ unsigned short lds[65536];  // 128 KiB

  const int tid  = threadIdx.x;
  const int lane = tid & 63;
  const int wv   = tid >> 6;      // 0..7
  const int wm   = wv & 1;        // M pair (rows wm*64 and 128+wm*64)
  const int wn   = wv >> 1;       // N quad (cols wn*32 and 128+wn*32)
  const int r32  = lane & 31;
  const int kh   = lane >> 5;     // k-half of fragment

  // bijective XCD chunk swizzle: 512 blocks -> 8 XCDs x (8 rows x 8 cols) chunks
  const int bid = blockIdx.x;
  const int xcd = bid & 7;
  const int loc = bid >> 3;                    // 0..63
  const int by  = (xcd >> 1) * 8 + (loc >> 3); // 0..31
  const int bx  = (xcd & 1) * 8 + (loc & 7);   // 0..15
  const int m0  = by * BM;
  const int n0  = bx * BN;

  // ---- staging geometry: instruction i covers chunk = wv*2+i (8 rows x 8 slots);
  // lane slot (srow = lane>>3, lane&7); source k-chunk = (lane&7) ^ srow ^ (chunk&7).
  const int srow = lane >> 3;
  const int l7   = lane & 7;
  const int rowoff0 = (wv * 2 + 0) * 8 + srow;
  const int rowoff1 = (wv * 2 + 1) * 8 + srow;
  const int sc0 = (l7 ^ srow ^ ((wv * 2 + 0) & 7)) * 8;
  const int sc1 = (l7 ^ srow ^ ((wv * 2 + 1) & 7)) * 8;
  const unsigned short* pA0 = A + (size_t)(m0 + rowoff0) * IN_F + sc0;
  const unsigned short* pA1 = A + (size_t)(m0 + rowoff1) * IN_F + sc1;
  const unsigned short* pB0 = B + (size_t)(n0 + rowoff0) * IN_F + sc0;
  const unsigned short* pB1 = B + (size_t)(n0 + rowoff1) * IN_F + sc1;

#define STAGE_A(bufi, h, kcol) do { \
    __builtin_amdgcn_global_load_lds((const GLOBAL_AS unsigned int*)(pA0 + (size_t)(h) * 128 * IN_F + (kcol)), \
        (LDS_AS unsigned int*)((char*)lds + (bufi) * 32768 + (h) * 16384 + (wv * 2 + 0) * 1024), 16, 0, 0); \
    __builtin_amdgcn_global_load_lds((const GLOBAL_AS unsigned int*)(pA1 + (size_t)(h) * 128 * IN_F + (kcol)), \
        (LDS_AS unsigned int*)((char*)lds + (bufi) * 32768 + (h) * 16384 + (wv * 2 + 1) * 1024), 16, 0, 0); \
  } while (0)

#define STAGE_B(bufi, h, kcol) do { \
    __builtin_amdgcn_global_load_lds((const GLOBAL_AS unsigned int*)(pB0 + (size_t)(h) * 128 * IN_F + (kcol)), \
        (LDS_AS unsigned int*)((char*)lds + 65536 + (bufi) * 32768 + (h) * 16384 + (wv * 2 + 0) * 1024), 16, 0, 0); \
    __builtin_amdgcn_global_load_lds((const GLOBAL_AS unsigned int*)(pB1 + (size_t)(h) * 128 * IN_F + (kcol)), \
        (LDS_AS unsigned int*)((char*)lds + 65536 + (bufi) * 32768 + (h) * 16384 + (wv * 2 + 1) * 1024), 16, 0, 0); \
  } while (0)

  // ---- read geometry: precomputed byte offsets (buf/half added as imm at the read)
  const int rA = wm * 64 + r32;   // A row-in-half for sm=0 (sm adds 32)
  const int rB = wn * 32 + r32;   // B row-in-half
  int offA[2][4];
  int offB[4];
#pragma unroll
  for (int sm = 0; sm < 2; ++sm) {
    const int fh = ((sm * 4) + (r32 >> 3)) & 7;   // ((row>>3)&7); wm*8 drops mod 8
#pragma unroll
    for (int k4 = 0; k4 < 4; ++k4) {
      const int pc = (2 * k4 + kh) ^ (r32 & 7) ^ fh;
      offA[sm][k4] = (rA + sm * 32) * 128 + pc * 16;
    }
  }
  {
    const int fh = ((wn * 4) + (r32 >> 3)) & 7;
#pragma unroll
    for (int k4 = 0; k4 < 4; ++k4) {
      const int pc = (2 * k4 + kh) ^ (r32 & 7) ^ fh;
      offB[k4] = 65536 + rB * 128 + pc * 16;
    }
  }

  bf16x8 af[2][4], bfr[2][4];

#define READ_A(bufi, qm) do { \
    _Pragma("unroll") for (int sm = 0; sm < 2; ++sm) \
    _Pragma("unroll") for (int k4 = 0; k4 < 4; ++k4) \
      af[sm][k4] = *(const bf16x8*)((const char*)lds + offA[sm][k4] + (bufi) * 32768 + (qm) * 16384); \
  } while (0)

#define READ_B(bufi, qn) do { \
    _Pragma("unroll") for (int k4 = 0; k4 < 4; ++k4) \
      bfr[qn][k4] = *(const bf16x8*)((const char*)lds + offB[k4] + (bufi) * 32768 + (qn) * 16384); \
  } while (0)

#define MFMA_Q(qm, qn) do { \
    __builtin_amdgcn_s_setprio(1); \
    _Pragma("unroll") for (int sm = 0; sm < 2; ++sm) \
    _Pragma("unroll") for (int k4 = 0; k4 < 4; ++k4) \
      acc[qm][sm][qn] = __builtin_amdgcn_mfma_f32_32x32x16_bf16(af[sm][k4], bfr[qn][k4], acc[qm][sm][qn], 0, 0, 0); \
    __builtin_amdgcn_s_setprio(0); \
  } while (0)

  f32x16 acc[2][2][2];
#pragma unroll
  for (int a = 0; a < 2; ++a)
#pragma unroll
    for (int b = 0; b < 2; ++b)
#pragma unroll
      for (int c = 0; c < 2; ++c)
        acc[a][b][c] = (f32x16)(0.0f);

  // ---- prologue: tile0 -> buf0 (A0,B0,B1,A1), tile1 -> buf1 (A0,B0,B1). 14 loads.
  STAGE_A(0, 0, 0); STAGE_B(0, 0, 0); STAGE_B(0, 1, 0); STAGE_A(0, 1, 0);
  STAGE_A(1, 0, BK); STAGE_B(1, 0, BK); STAGE_B(1, 1, BK);
  VMBAR(6);  // tile0 fully landed; tile1 A0/B0/B1 in flight

#pragma unroll 1
  for (int j = 0; j < NITER; ++j) {
    const int ku = (2 * j + 1) * BK;
    const int k2 = (2 * j + 2) * BK;
    const int k3 = (2 * j + 3) * BK;
    const bool more = (j < NITER - 1);

    // P1: tile t quadrant (Alow,Bleft); stage u.A1 (buf1.A.h1 last read prev P7,
    //     two end-phase barriers ago)
    READ_A(0, 0); READ_B(0, 0);
    STAGE_A(1, 1, ku);
    MFMA_Q(0, 0); BAR();

    // P2: (Alow,Bright); stage t+2.A0 (buf0.A.h0 last read P1, barrier between)
    READ_B(0, 1);
    if (more) STAGE_A(0, 0, k2);
    MFMA_Q(0, 1); BAR();

    // P3: (Ahigh,Bleft); stage t+2.B0 (buf0.B.h0 last read P1)
    READ_A(0, 1);
    if (more) STAGE_B(0, 0, k2);
    MFMA_Q(1, 0); BAR();

    // P4: (Ahigh,Bright); stage t+2.B1 (buf0.B.h1 last read P2); wait tile u landed
    if (more) STAGE_B(0, 1, k2);
    MFMA_Q(1, 1);
    if (more) { VMBAR(6); } else { VMBAR(0); }

    // P5: tile u quadrant (Alow,Bleft); stage t+2.A1 (buf0.A.h1 last read P3)
    READ_A(1, 0); READ_B(1, 0);
    if (more) STAGE_A(0, 1, k2);
    MFMA_Q(0, 0); BAR();

    // P6: (Alow,Bright); stage t+3.A0 (buf1.A.h0 last read P5)
    READ_B(1, 1);
    if (more) STAGE_A(1, 0, k3);
    MFMA_Q(0, 1); BAR();

    // P7: (Ahigh,Bleft); stage t+3.B0 (buf1.B.h0 last read P5)
    READ_A(1, 1);
    if (more) STAGE_B(1, 0, k3);
    MFMA_Q(1, 0); BAR();

    // P8: (Ahigh,Bright); stage t+3.B1 (buf1.B.h1 last read P6); wait tile t+2 landed
    if (more) STAGE_B(1, 1, k3);
    MFMA_Q(1, 1);
    if (more) { VMBAR(6); } else { BAR(); }
  }

  // ---- epilogue: C/D layout col = lane&31, row = (reg&3)+8*(reg>>2)+4*(lane>>5)
#pragma unroll
  for (int qm = 0; qm < 2; ++qm)
#pragma unroll
    for (int sm = 0; sm < 2; ++sm)
#pragma unroll
      for (int qn = 0; qn < 2; ++qn) {
        const int ncol = n0 + qn * 128 + wn * 32 + r32;
        const int mb   = m0 + qm * 128 + wm * 64 + sm * 32 + 4 * kh;
#pragma unroll
        for (int r = 0; r < 16; ++r) {
          const int mrow = mb + (r & 3) + 8 * (r >> 2);
          C[(size_t)mrow * OUT_F + ncol] = acc[qm][sm][qn][r];
        }
      }
}

extern "C" void kernel_launch(void* const* d_in, const int* in_sizes, int n_in,
                              void* d_out, int out_size, void* d_ws, size_t ws_size,
                              hipStream_t stream) {
  const float* x       = (const float*)d_in[0];   // [4,2048,4096] f32
  const int*   ternary = (const int*)d_in[1];     // [4096,4096] int {-1,0,1}
  const float* scales  = (const float*)d_in[2];   // [131072] f32
  float* out = (float*)d_out;                     // [4,2048,4096] f32

  unsigned short* xb = (unsigned short*)d_ws;                 // 67.1 MB
  unsigned short* wb = xb + (size_t)MROWS * IN_F;             // +33.6 MB

  prep_kernel<<<CVT_BLOCKS + DQ_BLOCKS, 256, 0, stream>>>(x, xb, ternary, scales, wb);

  gemm_bt_kernel<<<(MROWS / BM) * (OUT_F / BN), 512, 0, stream>>>(xb, wb, out);
}